// Round 18
// baseline (1088.611 us; speedup 1.0000x reference)
//
#include <hip/hip_runtime.h>
#include <hip/hip_bf16.h>

#define HH 64
#define XDIM 896
#define FF 512
#define LL 6
#define CC 40
#define CBSZ 512          // nodes per coarse bucket
#define SLACK 10240       // slots per bucket region
#define NSEG 13

typedef __bf16 bf16x8 __attribute__((ext_vector_type(8)));
typedef float f32x4 __attribute__((ext_vector_type(4)));

__device__ __forceinline__ unsigned short f2bf(float f){
  union{float f; unsigned int u;} v; v.f=f; unsigned int u=v.u;
  return (unsigned short)((u + 0x7fffu + ((u>>16)&1u))>>16);
}
__device__ __forceinline__ float bf2f(unsigned short u){
  union{unsigned int u; float f;} v; v.u = ((unsigned int)u)<<16; return v.f;
}
__device__ __forceinline__ float u2f(unsigned u){
  union{unsigned u; float f;} v; v.u=u; return v.f;
}

#define GLD16(gsrc, ldsdst) \
  __builtin_amdgcn_global_load_lds((const __attribute__((address_space(1))) unsigned int*)(gsrc), \
                                   (__attribute__((address_space(3))) unsigned int*)(ldsdst), 16, 0, 0)

// ---- fused prep: [0,256) edge-partition | [256,256+WB) wfrag | rest xcast ----
struct PrepP {
  const float* x; const int* ei;
  unsigned short* X; unsigned short* lin;   // lin = lin4 [4][(N+1)][16] chunk-major
  int* bcur; unsigned* tmp;
  const float* W[NSEG]; unsigned short* dst[NSEG];
  int nt[NSEG], nc[NSEG], tst[NSEG], tbs[NSEG], kbase[NSEG];
  int off[NSEG+1];
  int N, E, CH, NB, WB;
};

__global__ void __launch_bounds__(256) k_prep(PrepP P){
  __shared__ int hist[256];
  __shared__ int run[256];
  int t=threadIdx.x, b=blockIdx.x;
  if (b < 256){
    int E=P.E;
    int lo=b*P.CH, hi=lo+P.CH; if (hi>E) hi=E;
    for (int i=t;i<P.NB;i+=256) hist[i]=0;
    __syncthreads();
    for (int i=lo+t;i<hi;i+=256) atomicAdd(&hist[P.ei[E+i]>>9], 1);
    __syncthreads();
    for (int i=t;i<P.NB;i+=256) run[i]=i*SLACK+atomicAdd(&P.bcur[i], hist[i]);
    __syncthreads();
    for (int i=lo+t;i<hi;i+=256){
      int r=P.ei[i], c=P.ei[E+i];
      int pos=atomicAdd(&run[c>>9],1);
      P.tmp[pos]=((unsigned)r<<9)|(unsigned)(c&(CBSZ-1));
    }
  } else if (b < 256+P.WB){
    int idx=(b-256)*256+t;
    if (idx < P.off[NSEG]){
      int seg=0;
      while (idx>=P.off[seg+1]) ++seg;
      int li=idx-P.off[seg];
      int j=li&7, ln=(li>>3)&63, rem2=li>>9;
      int ntile=P.nt[seg], ncols=P.nc[seg];
      int nt_=rem2%ntile, kb=rem2/ntile;
      int k=P.kbase[seg]+kb*32+(ln>>4)*8+j;
      int c=nt_*16+(ln&15);
      float v=(c<ncols)? P.W[seg][(size_t)k*ncols+c] : 0.f;
      int di = ((kb*P.tst[seg] + P.tbs[seg] + nt_)*64 + ln)*8 + j;
      P.dst[seg][di]=f2bf(v);
    }
  } else {
    int i=(b-256-P.WB)*256+t;
    int total=P.N*(FF/4);
    if (i<total){
      int row=i/(FF/4), c4=(i%(FF/4))*4;
      float4 v=*(const float4*)(P.x+(size_t)row*FF+c4);
      ushort4 o; o.x=f2bf(v.x); o.y=f2bf(v.y); o.z=f2bf(v.z); o.w=f2bf(v.w);
      *(ushort4*)(P.X+(size_t)row*XDIM+c4)=o;
    }
  }
}

// ---- per-bucket: LDS count + scan -> offs/dinv; LDS-cursor scatter -> esrc ----
__global__ void __launch_bounds__(1024) k_build(const unsigned* __restrict__ tmp,
                                                const int* __restrict__ bcur,
                                                int* __restrict__ offsS, int* __restrict__ offsE,
                                                float* __restrict__ dinv,
                                                int* __restrict__ esrc, int N){
  __shared__ int cnt[CBSZ];
  __shared__ int run[CBSZ];
  int t=threadIdx.x, b=blockIdx.x;
  int n0=b*CBSZ;
  int nloc=N-n0; if (nloc>CBSZ) nloc=CBSZ;
  int wbase=b*SLACK;
  int wend=wbase + bcur[b];
  if (t<CBSZ) cnt[t]=0;
  __syncthreads();
  for (int i=wbase+t; i<wend; i+=1024) atomicAdd(&cnt[tmp[i]&(CBSZ-1u)],1);
  __syncthreads();
  int v = (t<CBSZ)? cnt[t] : 0;
  if (t<CBSZ) run[t]=v;
  __syncthreads();
  for (int o=1;o<CBSZ;o<<=1){
    int xx = (t<CBSZ && t>=o)? run[t-o] : 0;
    __syncthreads();
    if (t<CBSZ) run[t]+=xx;
    __syncthreads();
  }
  if (t<nloc){
    int s = wbase + (run[t]-v);
    offsS[n0+t]=s;
    offsE[n0+t]=s+v;
    dinv[n0+t]=rsqrtf((float)(v+1));
    run[t]=s;
  }
  __syncthreads();
  for (int i=wbase+t; i<wend; i+=1024){
    unsigned vv=tmp[i];
    int pos=atomicAdd(&run[vv&(CBSZ-1u)],1);
    esrc[pos]=(int)(vv>>9);
  }
}

// ---- big pass (R16): BM=128, BN=112 (7 tiles), 4 col-groups, A via global_load_lds ----
// block 0 also zero-fills row N of each lin4 chunk (tmp is dead by now).
struct GBP {
  const unsigned short* X; const unsigned short* WfBig;
  const float* dinv;
  unsigned short* pl[6];   // pl[0] = lin4 (dinv applied), 1..5 = raw bf16 partials [n][64]
  float* pF;               // [N,40] fp32 logits partial
  int N;
};

__global__ void __launch_bounds__(256) k_gbig(GBP P){
  __shared__ unsigned short Abuf[2][128*32];
  int t=threadIdx.x, lane=t&63, wv=t>>6;
  int bid = blockIdx.x;
  if (bid==0 && t<32){
    int c=t>>3, d=t&7;   // zero row N of each of the 4 lin4 chunks
    ((unsigned*)(P.pl[0] + ((size_t)c*(P.N+1) + P.N)*16))[d] = 0u;
  }
  int cg = bid & 3;
  long rb = (long)(bid>>2)*128;
  int tb = cg*7;                       // tiles [tb, tb+7); slots >=27 are pad
  int arow=lane&15, kgrp=lane>>4;

  int srow0 = wv*32 + (lane>>2);
  int srow1 = srow0 + 16;
  int scb   = 16*((lane&3) ^ (srow0&3));
  long gr0 = rb + srow0; if (gr0 > (long)P.N-1) gr0 = P.N-1;
  long gr1 = rb + srow1; if (gr1 > (long)P.N-1) gr1 = P.N-1;
  const char* gs0 = (const char*)P.X + gr0*(XDIM*2) + scb;
  const char* gs1 = (const char*)P.X + gr1*(XDIM*2) + scb;

  f32x4 acc0[7], acc1[7];
  #pragma unroll
  for (int i=0;i<7;i++){ f32x4 z={0.f,0.f,0.f,0.f}; acc0[i]=z; acc1[i]=z; }

  GLD16(gs0, &Abuf[0][(wv*2+0)*512]);
  GLD16(gs1, &Abuf[0][(wv*2+1)*512]);
  __syncthreads();

  int kofs = 16*(kgrp ^ (arow&3));
  for (int kb=0;kb<16;++kb){
    int cur = kb&1;
    if (kb<15){
      GLD16(gs0 + (kb+1)*64, &Abuf[cur^1][(wv*2+0)*512]);
      GLD16(gs1 + (kb+1)*64, &Abuf[cur^1][(wv*2+1)*512]);
    }
    const unsigned short* bp = P.WfBig + ((size_t)kb*28 + tb)*512 + lane*8;
    bf16x8 bv[7];
    #pragma unroll
    for (int tt=0;tt<7;++tt) bv[tt]=*(const bf16x8*)(bp + (size_t)tt*512);
    int lr0 = wv*32 + arow;
    bf16x8 a0 = *(const bf16x8*)((const char*)&Abuf[cur][0] + lr0*64 + kofs);
    bf16x8 a1 = *(const bf16x8*)((const char*)&Abuf[cur][0] + (lr0+16)*64 + kofs);
    #pragma unroll
    for (int tt=0;tt<7;++tt){
      acc0[tt]=__builtin_amdgcn_mfma_f32_16x16x32_bf16(a0,bv[tt],acc0[tt],0,0,0);
      acc1[tt]=__builtin_amdgcn_mfma_f32_16x16x32_bf16(a1,bv[tt],acc1[tt],0,0,0);
    }
    __syncthreads();
  }

  long row0 = rb + wv*32;
  #pragma unroll
  for (int tt=0;tt<7;++tt){
    int tg = tb+tt;
    if (tg >= 27) continue;
    #pragma unroll
    for (int j=0;j<4;++j){
      long rr=row0+kgrp*4+j;
      long rr1=rr+16;
      if (tg<24){
        int li=tg>>2, tloc=tg&3;
        if (li==0){
          // lin4 chunk-major: [tloc][(N+1)][16]
          if (rr<P.N)  P.pl[0][((size_t)tloc*(P.N+1)+rr )*16 + arow] = f2bf(acc0[tt][j]*P.dinv[rr]);
          if (rr1<P.N) P.pl[0][((size_t)tloc*(P.N+1)+rr1)*16 + arow] = f2bf(acc1[tt][j]*P.dinv[rr1]);
        } else {
          if (rr<P.N)  P.pl[li][(size_t)rr *64 + tloc*16 + arow] = f2bf(acc0[tt][j]);
          if (rr1<P.N) P.pl[li][(size_t)rr1*64 + tloc*16 + arow] = f2bf(acc1[tt][j]);
        }
      } else {
        int c=(tg-24)*16+arow;
        if (c<CC){
          if (rr<P.N)  P.pF[(size_t)rr*CC+c]=acc0[tt][j];
          if (rr1<P.N) P.pF[(size_t)rr1*CC+c]=acc1[tt][j];
        }
      }
    }
  }
}

// ---- layer-i gemm over H cols only: lin4 = dinv*(partial + X[:,512:512+64i] @ WfH) ----
__global__ void __launch_bounds__(256) k_gemmH(const unsigned short* __restrict__ X,
                                               const unsigned short* __restrict__ WfH,
                                               const unsigned short* __restrict__ part,
                                               const float* __restrict__ dinv,
                                               unsigned short* __restrict__ lin,
                                               int N, int nkb2){
  int lane = threadIdx.x & 63, wid = threadIdx.x >> 6;
  long row0 = (long)blockIdx.x*128 + wid*32;
  int arow = lane & 15, kgrp = lane >> 4;
  long r0 = row0 + arow;      if (r0 > (long)N-1) r0 = N-1;
  long r1 = row0 + 16 + arow; if (r1 > (long)N-1) r1 = N-1;
  const unsigned short* ap0 = X + (size_t)r0*XDIM + FF + kgrp*8;
  const unsigned short* ap1 = X + (size_t)r1*XDIM + FF + kgrp*8;
  const unsigned short* bptr = WfH + lane*8;
  f32x4 acc00={0.f,0.f,0.f,0.f}, acc01=acc00, acc02=acc00, acc03=acc00;
  f32x4 acc10=acc00, acc11=acc00, acc12=acc00, acc13=acc00;
  for (int kb=0; kb<nkb2; ++kb){
    bf16x8 a0 = *(const bf16x8*)(ap0 + (size_t)kb*32);
    bf16x8 a1 = *(const bf16x8*)(ap1 + (size_t)kb*32);
    const unsigned short* bp = bptr + (size_t)kb*2048;
    bf16x8 b0=*(const bf16x8*)bp, b1=*(const bf16x8*)(bp+512),
           b2=*(const bf16x8*)(bp+1024), b3=*(const bf16x8*)(bp+1536);
    acc00=__builtin_amdgcn_mfma_f32_16x16x32_bf16(a0,b0,acc00,0,0,0);
    acc10=__builtin_amdgcn_mfma_f32_16x16x32_bf16(a1,b0,acc10,0,0,0);
    acc01=__builtin_amdgcn_mfma_f32_16x16x32_bf16(a0,b1,acc01,0,0,0);
    acc11=__builtin_amdgcn_mfma_f32_16x16x32_bf16(a1,b1,acc11,0,0,0);
    acc02=__builtin_amdgcn_mfma_f32_16x16x32_bf16(a0,b2,acc02,0,0,0);
    acc12=__builtin_amdgcn_mfma_f32_16x16x32_bf16(a1,b2,acc12,0,0,0);
    acc03=__builtin_amdgcn_mfma_f32_16x16x32_bf16(a0,b3,acc03,0,0,0);
    acc13=__builtin_amdgcn_mfma_f32_16x16x32_bf16(a1,b3,acc13,0,0,0);
  }
  for (int j=0;j<4;++j){
    long rr = row0 + kgrp*4 + j;
    if (rr < N){
      float dv = dinv[rr];
      const unsigned short* pp = part + (size_t)rr*64 + arow;
      lin[((size_t)0*(N+1)+rr)*16 + arow] = f2bf((acc00[j]+bf2f(pp[0]))*dv);
      lin[((size_t)1*(N+1)+rr)*16 + arow] = f2bf((acc01[j]+bf2f(pp[16]))*dv);
      lin[((size_t)2*(N+1)+rr)*16 + arow] = f2bf((acc02[j]+bf2f(pp[32]))*dv);
      lin[((size_t)3*(N+1)+rr)*16 + arow] = f2bf((acc03[j]+bf2f(pp[48]))*dv);
    }
    long rr1 = rr + 16;
    if (rr1 < N){
      float dv = dinv[rr1];
      const unsigned short* pp = part + (size_t)rr1*64 + arow;
      lin[((size_t)0*(N+1)+rr1)*16 + arow] = f2bf((acc10[j]+bf2f(pp[0]))*dv);
      lin[((size_t)1*(N+1)+rr1)*16 + arow] = f2bf((acc11[j]+bf2f(pp[16]))*dv);
      lin[((size_t)2*(N+1)+rr1)*16 + arow] = f2bf((acc12[j]+bf2f(pp[32]))*dv);
      lin[((size_t)3*(N+1)+rr1)*16 + arow] = f2bf((acc13[j]+bf2f(pp[48]))*dv);
    }
  }
}

// ---- aggregate v2: 4 feature-chunk passes; chunk table (3.2MB) is L2-resident ----
// grid = 4*nb4 blocks, chunk-major. lane=(sub 0..15 edge slot, fj 0..3 feat quad).
__global__ void __launch_bounds__(256) k_agg(const unsigned short* __restrict__ lin4,
                                             const int* __restrict__ offsS,
                                             const int* __restrict__ offsE,
                                             const int* __restrict__ esrc,
                                             const float* __restrict__ dinv,
                                             const float* __restrict__ bias,
                                             unsigned short* __restrict__ X,
                                             int colbase, int N, int nb4){
  int lane = threadIdx.x & 63, wid = threadIdx.x >> 6;
  int chunk = blockIdx.x / nb4;
  int nbid  = blockIdx.x - chunk*nb4;
  int n = nbid*4 + wid;
  if (n >= N) return;
  int sub = lane >> 2;         // edge slot 0..15
  int fj  = lane & 3;          // feature quad within chunk
  const unsigned short* lq = lin4 + (size_t)chunk*(N+1)*16 + fj*4;
  float a0=0.f,a1=0.f,a2=0.f,a3=0.f;
  int s = offsS[n], e = offsE[n];
  int base = s;
  for (; base + 32 <= e; base += 32){
    int sx0 = esrc[base + sub];
    int sx1 = esrc[base + 16 + sub];
    uint2 v0 = *(const uint2*)(lq + (size_t)sx0*16);
    uint2 v1 = *(const uint2*)(lq + (size_t)sx1*16);
    a0 += u2f(v0.x<<16); a1 += u2f(v0.x&0xffff0000u);
    a2 += u2f(v0.y<<16); a3 += u2f(v0.y&0xffff0000u);
    a0 += u2f(v1.x<<16); a1 += u2f(v1.x&0xffff0000u);
    a2 += u2f(v1.y<<16); a3 += u2f(v1.y&0xffff0000u);
  }
  if (base < e){
    int rem = e - base;        // 1..31
    int sx0 = esrc[base + sub];
    sx0 = (sub < rem) ? sx0 : (int)N;
    uint2 v0 = *(const uint2*)(lq + (size_t)sx0*16);
    a0 += u2f(v0.x<<16); a1 += u2f(v0.x&0xffff0000u);
    a2 += u2f(v0.y<<16); a3 += u2f(v0.y&0xffff0000u);
    if (rem > 16){
      int sx1 = esrc[base + 16 + sub];
      sx1 = (16 + sub < rem) ? sx1 : (int)N;
      uint2 v1 = *(const uint2*)(lq + (size_t)sx1*16);
      a0 += u2f(v1.x<<16); a1 += u2f(v1.x&0xffff0000u);
      a2 += u2f(v1.y<<16); a3 += u2f(v1.y&0xffff0000u);
    }
  }
  // reduce across sub (lane bits 2..5)
  a0 += __shfl_xor(a0,4,64); a0 += __shfl_xor(a0,8,64); a0 += __shfl_xor(a0,16,64); a0 += __shfl_xor(a0,32,64);
  a1 += __shfl_xor(a1,4,64); a1 += __shfl_xor(a1,8,64); a1 += __shfl_xor(a1,16,64); a1 += __shfl_xor(a1,32,64);
  a2 += __shfl_xor(a2,4,64); a2 += __shfl_xor(a2,8,64); a2 += __shfl_xor(a2,16,64); a2 += __shfl_xor(a2,32,64);
  a3 += __shfl_xor(a3,4,64); a3 += __shfl_xor(a3,8,64); a3 += __shfl_xor(a3,16,64); a3 += __shfl_xor(a3,32,64);
  // self-loop
  uint2 vs = *(const uint2*)(lq + (size_t)n*16);
  a0 += u2f(vs.x<<16); a1 += u2f(vs.x&0xffff0000u);
  a2 += u2f(vs.y<<16); a3 += u2f(vs.y&0xffff0000u);
  float dv = dinv[n];
  float4 b4 = *(const float4*)(bias + chunk*16 + fj*4);
  float h0 = fmaxf(a0*dv + b4.x, 0.f);
  float h1 = fmaxf(a1*dv + b4.y, 0.f);
  float h2 = fmaxf(a2*dv + b4.z, 0.f);
  float h3 = fmaxf(a3*dv + b4.w, 0.f);
  if (sub == 0){
    ushort4 o; o.x=f2bf(h0); o.y=f2bf(h1); o.z=f2bf(h2); o.w=f2bf(h3);
    *(ushort4*)(X + (size_t)n*XDIM + colbase + chunk*16 + fj*4) = o;
  }
}

// ---- final: logits = pF + X[:,512:896] @ WfLinH + blin, log_softmax ----
__global__ void __launch_bounds__(256) k_final(const unsigned short* __restrict__ X,
                                               const unsigned short* __restrict__ Wf,
                                               const float* __restrict__ pF,
                                               const float* __restrict__ blin,
                                               float* __restrict__ out, int N){
  int lane=threadIdx.x&63, wid=threadIdx.x>>6;
  long row0=(long)blockIdx.x*64 + wid*16;
  int c0=lane&15, g=lane>>4;
  long r=row0+c0; if (r > (long)N-1) r = N-1;
  const unsigned short* aptr = X + (size_t)r*XDIM + FF + g*8;
  const unsigned short* bptr = Wf + lane*8;
  f32x4 acc0={0.f,0.f,0.f,0.f}, acc1=acc0, acc2=acc0;
  const int nkb = (XDIM-FF)/32;  // 12
  for (int kb=0;kb<nkb;++kb){
    bf16x8 a=*(const bf16x8*)(aptr+(size_t)kb*32);
    const unsigned short* bp = bptr + (size_t)kb*1536;
    bf16x8 b0=*(const bf16x8*)bp, b1=*(const bf16x8*)(bp+512), b2=*(const bf16x8*)(bp+1024);
    acc0=__builtin_amdgcn_mfma_f32_16x16x32_bf16(a,b0,acc0,0,0,0);
    acc1=__builtin_amdgcn_mfma_f32_16x16x32_bf16(a,b1,acc1,0,0,0);
    acc2=__builtin_amdgcn_mfma_f32_16x16x32_bf16(a,b2,acc2,0,0,0);
  }
  float bl0 = blin[c0], bl1 = blin[16+c0];
  bool v2ok = (c0 < 8);
  float bl2 = v2ok ? blin[32+c0] : 0.f;
  for (int j=0;j<4;++j){
    long rr = row0 + g*4 + j;
    long rrc = rr < N ? rr : (long)N-1;
    const float* pp = pF + (size_t)rrc*CC;
    float v0 = acc0[j]+bl0+pp[c0], v1 = acc1[j]+bl1+pp[16+c0];
    float v2 = v2ok ? (acc2[j]+bl2+pp[32+c0]) : -1e30f;
    float m = fmaxf(fmaxf(v0,v1),v2);
    m = fmaxf(m, __shfl_xor(m,1,64));
    m = fmaxf(m, __shfl_xor(m,2,64));
    m = fmaxf(m, __shfl_xor(m,4,64));
    m = fmaxf(m, __shfl_xor(m,8,64));
    float sEx = expf(v0-m)+expf(v1-m)+(v2ok?expf(v2-m):0.f);
    sEx += __shfl_xor(sEx,1,64);
    sEx += __shfl_xor(sEx,2,64);
    sEx += __shfl_xor(sEx,4,64);
    sEx += __shfl_xor(sEx,8,64);
    float lse = m + logf(sEx);
    if (rr < N){
      out[(size_t)rr*CC + c0]      = v0 - lse;
      out[(size_t)rr*CC + 16 + c0] = v1 - lse;
      if (v2ok) out[(size_t)rr*CC + 32 + c0] = v2 - lse;
    }
  }
}

extern "C" void kernel_launch(void* const* d_in, const int* in_sizes, int n_in,
                              void* d_out, int out_size, void* d_ws, size_t ws_size,
                              hipStream_t stream){
  const float* x = (const float*)d_in[0];
  const int* ei = (const int*)d_in[1];
  const float* Wl[LL]; const float* bl[LL];
  for (int i=0;i<LL;i++){ Wl[i]=(const float*)d_in[2+2*i]; bl[i]=(const float*)d_in[3+2*i]; }
  const float* Wlin = (const float*)d_in[2+2*LL];
  const float* blin = (const float*)d_in[3+2*LL];
  float* out = (float*)d_out;
  const int N = in_sizes[0]/FF;
  const int E = in_sizes[1]/2;
  const int NB = (N+CBSZ-1)/CBSZ;

  char* p = (char*)d_ws;
  auto alloc = [&](size_t bb)->char*{ char* r=p; p += (bb+255)&~(size_t)255; return r; };
  unsigned short* X   = (unsigned short*)alloc((size_t)N*XDIM*2);
  unsigned short* lin = (unsigned short*)alloc((size_t)4*(N+1)*16*2);  // lin4 chunk-major
  unsigned* tmp = (unsigned*)lin;  // alias: tmp dead before gbig writes lin
  unsigned short* WfBig  = (unsigned short*)alloc((size_t)16*28*512*2);
  unsigned short* WfH[LL];   // index 1..5
  for (int i=1;i<LL;i++) WfH[i]=(unsigned short*)alloc((size_t)(2*i)*4*512*2);
  unsigned short* WfLinH = (unsigned short*)alloc((size_t)12*3*512*2);
  unsigned short* part[LL];  // index 1..5
  for (int i=1;i<LL;i++) part[i]=(unsigned short*)alloc((size_t)N*64*2);
  float* pF    = (float*)alloc((size_t)N*CC*4);
  float* dinv  = (float*)alloc((size_t)N*4);
  int* offsS   = (int*)alloc((size_t)N*4);
  int* offsE   = (int*)alloc((size_t)N*4);
  int* bcur    = (int*)alloc((size_t)NB*4);
  int* esrc    = (int*)alloc(((size_t)NB*SLACK+64)*4);

  PrepP P;
  P.x=x; P.ei=ei; P.X=X; P.lin=lin; P.bcur=bcur; P.tmp=tmp;
  int off=0, sg=0;
  for (int i=0;i<LL;i++){
    P.W[sg]=Wl[i]; P.dst[sg]=WfBig; P.nt[sg]=4; P.nc[sg]=HH;
    P.tst[sg]=28; P.tbs[sg]=4*i; P.kbase[sg]=0;
    P.off[sg]=off; off += 16*4*512; ++sg;
  }
  P.W[sg]=Wlin; P.dst[sg]=WfBig; P.nt[sg]=3; P.nc[sg]=CC;
  P.tst[sg]=28; P.tbs[sg]=24; P.kbase[sg]=0;
  P.off[sg]=off; off += 16*3*512; ++sg;
  for (int i=1;i<LL;i++){
    P.W[sg]=Wl[i]; P.dst[sg]=WfH[i]; P.nt[sg]=4; P.nc[sg]=HH;
    P.tst[sg]=4; P.tbs[sg]=0; P.kbase[sg]=FF;
    P.off[sg]=off; off += (2*i)*4*512; ++sg;
  }
  P.W[sg]=Wlin; P.dst[sg]=WfLinH; P.nt[sg]=3; P.nc[sg]=CC;
  P.tst[sg]=3; P.tbs[sg]=0; P.kbase[sg]=FF;
  P.off[sg]=off; off += 12*3*512; ++sg;
  P.off[sg]=off;
  P.N=N; P.E=E; P.CH=(E+255)/256; P.NB=NB; P.WB=(off+255)/256;
  int XB=(N*(FF/4)+255)/256;

  hipMemsetAsync(bcur, 0, (size_t)NB*4, stream);
  k_prep <<<256 + P.WB + XB, 256, 0, stream>>>(P);
  k_build<<<NB, 1024, 0, stream>>>(tmp, bcur, offsS, offsE, dinv, esrc, N);

  GBP G;
  G.X=X; G.WfBig=WfBig; G.dinv=dinv;
  G.pl[0]=lin;
  for (int i=1;i<LL;i++) G.pl[i]=part[i];
  G.pF=pF; G.N=N;
  int rbks = (N+127)/128;
  k_gbig<<<rbks*4, 256, 0, stream>>>(G);

  int gb = (N+127)/128;
  int ab = (N+3)/4;
  for (int i=0;i<LL;i++){
    if (i>0) k_gemmH<<<gb,256,0,stream>>>(X, WfH[i], part[i], dinv, lin, N, 2*i);
    k_agg<<<4*ab,256,0,stream>>>(lin, offsS, offsE, esrc, dinv, bl[i], X, FF+HH*i, N, ab);
  }
  k_final<<<(N+63)/64,256,0,stream>>>(X, WfLinH, pF, blin, out, N);
}

// Round 19
// 584.602 us; speedup vs baseline: 1.8621x; 1.8621x over previous
//
#include <hip/hip_runtime.h>
#include <hip/hip_bf16.h>

#define HH 64
#define XDIM 896
#define FF 512
#define LL 6
#define CC 40
#define CBSZ 512          // nodes per coarse bucket
#define SLACK 10240       // slots per bucket region
#define NSEG 13

typedef __bf16 bf16x8 __attribute__((ext_vector_type(8)));
typedef float f32x4 __attribute__((ext_vector_type(4)));

__device__ __forceinline__ unsigned short f2bf(float f){
  union{float f; unsigned int u;} v; v.f=f; unsigned int u=v.u;
  return (unsigned short)((u + 0x7fffu + ((u>>16)&1u))>>16);
}
__device__ __forceinline__ float bf2f(unsigned short u){
  union{unsigned int u; float f;} v; v.u = ((unsigned int)u)<<16; return v.f;
}
__device__ __forceinline__ float u2f(unsigned u){
  union{unsigned u; float f;} v; v.u=u; return v.f;
}

#define GLD16(gsrc, ldsdst) \
  __builtin_amdgcn_global_load_lds((const __attribute__((address_space(1))) unsigned int*)(gsrc), \
                                   (__attribute__((address_space(3))) unsigned int*)(ldsdst), 16, 0, 0)

// ---- fused prep: [0,256) edge-partition | [256,256+WB) wfrag | rest xcast ----
struct PrepP {
  const float* x; const int* ei;
  unsigned short* X; unsigned short* lin;   // lin row-major [(N+1)][64], row N = zeros
  int* bcur; unsigned* tmp;
  const float* W[NSEG]; unsigned short* dst[NSEG];
  int nt[NSEG], nc[NSEG], tst[NSEG], tbs[NSEG], kbase[NSEG];
  int off[NSEG+1];
  int N, E, CH, NB, WB;
};

__global__ void __launch_bounds__(256) k_prep(PrepP P){
  __shared__ int hist[256];
  __shared__ int run[256];
  int t=threadIdx.x, b=blockIdx.x;
  if (b < 256){
    int E=P.E;
    int lo=b*P.CH, hi=lo+P.CH; if (hi>E) hi=E;
    for (int i=t;i<P.NB;i+=256) hist[i]=0;
    __syncthreads();
    for (int i=lo+t;i<hi;i+=256) atomicAdd(&hist[P.ei[E+i]>>9], 1);
    __syncthreads();
    for (int i=t;i<P.NB;i+=256) run[i]=i*SLACK+atomicAdd(&P.bcur[i], hist[i]);
    __syncthreads();
    for (int i=lo+t;i<hi;i+=256){
      int r=P.ei[i], c=P.ei[E+i];
      int pos=atomicAdd(&run[c>>9],1);
      P.tmp[pos]=((unsigned)r<<9)|(unsigned)(c&(CBSZ-1));
    }
  } else if (b < 256+P.WB){
    int idx=(b-256)*256+t;
    if (idx < P.off[NSEG]){
      int seg=0;
      while (idx>=P.off[seg+1]) ++seg;
      int li=idx-P.off[seg];
      int j=li&7, ln=(li>>3)&63, rem2=li>>9;
      int ntile=P.nt[seg], ncols=P.nc[seg];
      int nt_=rem2%ntile, kb=rem2/ntile;
      int k=P.kbase[seg]+kb*32+(ln>>4)*8+j;
      int c=nt_*16+(ln&15);
      float v=(c<ncols)? P.W[seg][(size_t)k*ncols+c] : 0.f;
      int di = ((kb*P.tst[seg] + P.tbs[seg] + nt_)*64 + ln)*8 + j;
      P.dst[seg][di]=f2bf(v);
    }
  } else {
    int i=(b-256-P.WB)*256+t;
    if (i<32) ((unsigned*)(P.lin+(size_t)P.N*64))[i]=0u;  // zero row N (beyond tmp's 8MB)
    int total=P.N*(FF/4);
    if (i<total){
      int row=i/(FF/4), c4=(i%(FF/4))*4;
      float4 v=*(const float4*)(P.x+(size_t)row*FF+c4);
      ushort4 o; o.x=f2bf(v.x); o.y=f2bf(v.y); o.z=f2bf(v.z); o.w=f2bf(v.w);
      *(ushort4*)(P.X+(size_t)row*XDIM+c4)=o;
    }
  }
}

// ---- per-bucket: LDS count + scan -> offs/dinv; LDS-cursor scatter -> esrc ----
__global__ void __launch_bounds__(1024) k_build(const unsigned* __restrict__ tmp,
                                                const int* __restrict__ bcur,
                                                int* __restrict__ offsS, int* __restrict__ offsE,
                                                float* __restrict__ dinv,
                                                int* __restrict__ esrc, int N){
  __shared__ int cnt[CBSZ];
  __shared__ int run[CBSZ];
  int t=threadIdx.x, b=blockIdx.x;
  int n0=b*CBSZ;
  int nloc=N-n0; if (nloc>CBSZ) nloc=CBSZ;
  int wbase=b*SLACK;
  int wend=wbase + bcur[b];
  if (t<CBSZ) cnt[t]=0;
  __syncthreads();
  for (int i=wbase+t; i<wend; i+=1024) atomicAdd(&cnt[tmp[i]&(CBSZ-1u)],1);
  __syncthreads();
  int v = (t<CBSZ)? cnt[t] : 0;
  if (t<CBSZ) run[t]=v;
  __syncthreads();
  for (int o=1;o<CBSZ;o<<=1){
    int xx = (t<CBSZ && t>=o)? run[t-o] : 0;
    __syncthreads();
    if (t<CBSZ) run[t]+=xx;
    __syncthreads();
  }
  if (t<nloc){
    int s = wbase + (run[t]-v);
    offsS[n0+t]=s;
    offsE[n0+t]=s+v;
    dinv[n0+t]=rsqrtf((float)(v+1));
    run[t]=s;
  }
  __syncthreads();
  for (int i=wbase+t; i<wend; i+=1024){
    unsigned vv=tmp[i];
    int pos=atomicAdd(&run[vv&(CBSZ-1u)],1);
    esrc[pos]=(int)(vv>>9);
  }
}

// ---- big pass v7 (hybrid): BM=32, 4 waves x 7 tiles over SAME 32 rows;
//      A double-buffered in LDS (waves 0-1 stage 1KB each, swizzled), 1x A fetch ----
struct GBP {
  const unsigned short* X; const unsigned short* WfBig;
  const float* dinv;
  unsigned short* pl[6];   // pl[0] = lin (dinv applied), 1..5 = raw bf16 partials [n][64]
  float* pF;               // [N,40] fp32 logits partial
  int N;
};

__global__ void __launch_bounds__(256) k_gbig(GBP P){
  __shared__ unsigned short Abuf[2][1024];   // 2 x 2KB (32 rows x 64B)
  int t=threadIdx.x, lane=t&63, wv=t>>6;
  int tb = wv*7;              // tiles [tb, tb+7); slots >=27 pad (write-skipped)
  long rb = (long)blockIdx.x*32;
  int arow=lane&15, kgrp=lane>>4;

  // staging (waves 0,1 only): wave wv stages local rows wv*16 .. wv*16+15
  const char* gs = nullptr;
  if (wv < 2){
    int srow = wv*16 + (lane>>2);
    int scb  = 16*((lane&3) ^ (srow&3));      // swizzled source byte within 64B row-chunk
    long gr = rb + srow; if (gr > (long)P.N-1) gr = P.N-1;
    gs = (const char*)P.X + gr*(XDIM*2) + scb;
  }

  f32x4 acc0[7], acc1[7];
  #pragma unroll
  for (int i=0;i<7;i++){ f32x4 z={0.f,0.f,0.f,0.f}; acc0[i]=z; acc1[i]=z; }

  if (wv < 2) GLD16(gs, &Abuf[0][wv*512]);
  __syncthreads();

  int kof0 = 16*(kgrp ^ (arow&3));        // row arow:     (arow+16)&3 == arow&3
  for (int kb=0;kb<16;++kb){
    int cur = kb&1;
    if (kb<15 && wv<2) GLD16(gs + (kb+1)*64, &Abuf[cur^1][wv*512]);
    const unsigned short* bp = P.WfBig + ((size_t)kb*28 + tb)*512 + lane*8;
    bf16x8 bv[7];
    #pragma unroll
    for (int tt=0;tt<7;++tt) bv[tt]=*(const bf16x8*)(bp + (size_t)tt*512);
    bf16x8 a0 = *(const bf16x8*)((const char*)&Abuf[cur][0] + arow*64 + kof0);
    bf16x8 a1 = *(const bf16x8*)((const char*)&Abuf[cur][0] + (arow+16)*64 + kof0);
    #pragma unroll
    for (int tt=0;tt<7;++tt){
      acc0[tt]=__builtin_amdgcn_mfma_f32_16x16x32_bf16(a0,bv[tt],acc0[tt],0,0,0);
      acc1[tt]=__builtin_amdgcn_mfma_f32_16x16x32_bf16(a1,bv[tt],acc1[tt],0,0,0);
    }
    __syncthreads();
  }

  long row0 = rb;
  #pragma unroll
  for (int tt=0;tt<7;++tt){
    int tg = tb+tt;
    if (tg >= 27) continue;    // pad slot
    #pragma unroll
    for (int j=0;j<4;++j){
      long rr=row0+kgrp*4+j;
      long rr1=rr+16;
      if (tg<24){
        int li=tg>>2, tloc=tg&3;
        if (rr<P.N){
          float s = (li==0) ? P.dinv[rr] : 1.f;
          P.pl[li][(size_t)rr*64 + tloc*16 + arow] = f2bf(acc0[tt][j]*s);
        }
        if (rr1<P.N){
          float s = (li==0) ? P.dinv[rr1] : 1.f;
          P.pl[li][(size_t)rr1*64 + tloc*16 + arow] = f2bf(acc1[tt][j]*s);
        }
      } else {
        int c=(tg-24)*16+arow;
        if (c<CC){
          if (rr<P.N)  P.pF[(size_t)rr*CC+c]=acc0[tt][j];
          if (rr1<P.N) P.pF[(size_t)rr1*CC+c]=acc1[tt][j];
        }
      }
    }
  }
}

// ---- layer-i gemm over H cols only: lin = dinv*(partial + X[:,512:512+64i] @ WfH) ----
__global__ void __launch_bounds__(256) k_gemmH(const unsigned short* __restrict__ X,
                                               const unsigned short* __restrict__ WfH,
                                               const unsigned short* __restrict__ part,
                                               const float* __restrict__ dinv,
                                               unsigned short* __restrict__ lin,
                                               int N, int nkb2){
  int lane = threadIdx.x & 63, wid = threadIdx.x >> 6;
  long row0 = (long)blockIdx.x*128 + wid*32;
  int arow = lane & 15, kgrp = lane >> 4;
  long r0 = row0 + arow;      if (r0 > (long)N-1) r0 = N-1;
  long r1 = row0 + 16 + arow; if (r1 > (long)N-1) r1 = N-1;
  const unsigned short* ap0 = X + (size_t)r0*XDIM + FF + kgrp*8;
  const unsigned short* ap1 = X + (size_t)r1*XDIM + FF + kgrp*8;
  const unsigned short* bptr = WfH + lane*8;
  f32x4 acc00={0.f,0.f,0.f,0.f}, acc01=acc00, acc02=acc00, acc03=acc00;
  f32x4 acc10=acc00, acc11=acc00, acc12=acc00, acc13=acc00;
  for (int kb=0; kb<nkb2; ++kb){
    bf16x8 a0 = *(const bf16x8*)(ap0 + (size_t)kb*32);
    bf16x8 a1 = *(const bf16x8*)(ap1 + (size_t)kb*32);
    const unsigned short* bp = bptr + (size_t)kb*2048;
    bf16x8 b0=*(const bf16x8*)bp, b1=*(const bf16x8*)(bp+512),
           b2=*(const bf16x8*)(bp+1024), b3=*(const bf16x8*)(bp+1536);
    acc00=__builtin_amdgcn_mfma_f32_16x16x32_bf16(a0,b0,acc00,0,0,0);
    acc10=__builtin_amdgcn_mfma_f32_16x16x32_bf16(a1,b0,acc10,0,0,0);
    acc01=__builtin_amdgcn_mfma_f32_16x16x32_bf16(a0,b1,acc01,0,0,0);
    acc11=__builtin_amdgcn_mfma_f32_16x16x32_bf16(a1,b1,acc11,0,0,0);
    acc02=__builtin_amdgcn_mfma_f32_16x16x32_bf16(a0,b2,acc02,0,0,0);
    acc12=__builtin_amdgcn_mfma_f32_16x16x32_bf16(a1,b2,acc12,0,0,0);
    acc03=__builtin_amdgcn_mfma_f32_16x16x32_bf16(a0,b3,acc03,0,0,0);
    acc13=__builtin_amdgcn_mfma_f32_16x16x32_bf16(a1,b3,acc13,0,0,0);
  }
  for (int j=0;j<4;++j){
    long rr = row0 + kgrp*4 + j;
    if (rr < N){
      float dv = dinv[rr];
      const unsigned short* pp = part + (size_t)rr*64 + arow;
      unsigned short* lp = lin + (size_t)rr*64 + arow;
      lp[0]  = f2bf((acc00[j]+bf2f(pp[0]))*dv);
      lp[16] = f2bf((acc01[j]+bf2f(pp[16]))*dv);
      lp[32] = f2bf((acc02[j]+bf2f(pp[32]))*dv);
      lp[48] = f2bf((acc03[j]+bf2f(pp[48]))*dv);
    }
    long rr1 = rr + 16;
    if (rr1 < N){
      float dv = dinv[rr1];
      const unsigned short* pp = part + (size_t)rr1*64 + arow;
      unsigned short* lp = lin + (size_t)rr1*64 + arow;
      lp[0]  = f2bf((acc10[j]+bf2f(pp[0]))*dv);
      lp[16] = f2bf((acc11[j]+bf2f(pp[16]))*dv);
      lp[32] = f2bf((acc12[j]+bf2f(pp[32]))*dv);
      lp[48] = f2bf((acc13[j]+bf2f(pp[48]))*dv);
    }
  }
}

// ---- aggregate (R5-proven): 1 wave/node; lane=(sub 0..3, fq 0..15); uint2 gathers ----
__global__ void __launch_bounds__(256) k_agg(const unsigned short* __restrict__ lin,
                                             const int* __restrict__ offsS,
                                             const int* __restrict__ offsE,
                                             const int* __restrict__ esrc,
                                             const float* __restrict__ dinv,
                                             const float* __restrict__ bias,
                                             unsigned short* __restrict__ X,
                                             int colbase, int N){
  int lane = threadIdx.x & 63, wid = threadIdx.x >> 6;
  int n = blockIdx.x*4 + wid;
  if (n >= N) return;
  int sub = lane >> 4;
  int fq  = lane & 15;
  const unsigned short* lq = lin + fq*4;
  float a0=0.f, a1=0.f, a2=0.f, a3=0.f;
  int s = offsS[n], e = offsE[n];
  int base = s;
  for (; base + 32 <= e; base += 32){
    #pragma unroll
    for (int k=0;k<8;++k){
      int sx = esrc[base + 4*k + sub];
      uint2 v = *(const uint2*)(lq + (size_t)sx*64);
      a0 += u2f(v.x<<16); a1 += u2f(v.x&0xffff0000u);
      a2 += u2f(v.y<<16); a3 += u2f(v.y&0xffff0000u);
    }
  }
  if (base < e){
    int rem = e - base;
    if (rem > 16){
      #pragma unroll
      for (int k=0;k<8;++k){
        int idx = 4*k + sub;
        int sx = esrc[base + idx];
        sx = (idx < rem) ? sx : (int)N;
        uint2 v = *(const uint2*)(lq + (size_t)sx*64);
        a0 += u2f(v.x<<16); a1 += u2f(v.x&0xffff0000u);
        a2 += u2f(v.y<<16); a3 += u2f(v.y&0xffff0000u);
      }
    } else {
      #pragma unroll
      for (int k=0;k<4;++k){
        int idx = 4*k + sub;
        int sx = esrc[base + idx];
        sx = (idx < rem) ? sx : (int)N;
        uint2 v = *(const uint2*)(lq + (size_t)sx*64);
        a0 += u2f(v.x<<16); a1 += u2f(v.x&0xffff0000u);
        a2 += u2f(v.y<<16); a3 += u2f(v.y&0xffff0000u);
      }
    }
  }
  a0 += __shfl_xor(a0,16,64); a0 += __shfl_xor(a0,32,64);
  a1 += __shfl_xor(a1,16,64); a1 += __shfl_xor(a1,32,64);
  a2 += __shfl_xor(a2,16,64); a2 += __shfl_xor(a2,32,64);
  a3 += __shfl_xor(a3,16,64); a3 += __shfl_xor(a3,32,64);
  uint2 vs = *(const uint2*)(lq + (size_t)n*64);
  a0 += u2f(vs.x<<16); a1 += u2f(vs.x&0xffff0000u);
  a2 += u2f(vs.y<<16); a3 += u2f(vs.y&0xffff0000u);
  float dv = dinv[n];
  float4 b4 = *(const float4*)(bias + fq*4);
  float h0 = fmaxf(a0*dv + b4.x, 0.f);
  float h1 = fmaxf(a1*dv + b4.y, 0.f);
  float h2 = fmaxf(a2*dv + b4.z, 0.f);
  float h3 = fmaxf(a3*dv + b4.w, 0.f);
  if (sub == 0){
    ushort4 o; o.x=f2bf(h0); o.y=f2bf(h1); o.z=f2bf(h2); o.w=f2bf(h3);
    *(ushort4*)(X + (size_t)n*XDIM + colbase + fq*4) = o;
  }
}

// ---- final: logits = pF + X[:,512:896] @ WfLinH + blin, log_softmax ----
__global__ void __launch_bounds__(256) k_final(const unsigned short* __restrict__ X,
                                               const unsigned short* __restrict__ Wf,
                                               const float* __restrict__ pF,
                                               const float* __restrict__ blin,
                                               float* __restrict__ out, int N){
  int lane=threadIdx.x&63, wid=threadIdx.x>>6;
  long row0=(long)blockIdx.x*64 + wid*16;
  int c0=lane&15, g=lane>>4;
  long r=row0+c0; if (r > (long)N-1) r = N-1;
  const unsigned short* aptr = X + (size_t)r*XDIM + FF + g*8;
  const unsigned short* bptr = Wf + lane*8;
  f32x4 acc0={0.f,0.f,0.f,0.f}, acc1=acc0, acc2=acc0;
  const int nkb = (XDIM-FF)/32;  // 12
  for (int kb=0;kb<nkb;++kb){
    bf16x8 a=*(const bf16x8*)(aptr+(size_t)kb*32);
    const unsigned short* bp = bptr + (size_t)kb*1536;
    bf16x8 b0=*(const bf16x8*)bp, b1=*(const bf16x8*)(bp+512), b2=*(const bf16x8*)(bp+1024);
    acc0=__builtin_amdgcn_mfma_f32_16x16x32_bf16(a,b0,acc0,0,0,0);
    acc1=__builtin_amdgcn_mfma_f32_16x16x32_bf16(a,b1,acc1,0,0,0);
    acc2=__builtin_amdgcn_mfma_f32_16x16x32_bf16(a,b2,acc2,0,0,0);
  }
  float bl0 = blin[c0], bl1 = blin[16+c0];
  bool v2ok = (c0 < 8);
  float bl2 = v2ok ? blin[32+c0] : 0.f;
  for (int j=0;j<4;++j){
    long rr = row0 + g*4 + j;
    long rrc = rr < N ? rr : (long)N-1;
    const float* pp = pF + (size_t)rrc*CC;
    float v0 = acc0[j]+bl0+pp[c0], v1 = acc1[j]+bl1+pp[16+c0];
    float v2 = v2ok ? (acc2[j]+bl2+pp[32+c0]) : -1e30f;
    float m = fmaxf(fmaxf(v0,v1),v2);
    m = fmaxf(m, __shfl_xor(m,1,64));
    m = fmaxf(m, __shfl_xor(m,2,64));
    m = fmaxf(m, __shfl_xor(m,4,64));
    m = fmaxf(m, __shfl_xor(m,8,64));
    float sEx = expf(v0-m)+expf(v1-m)+(v2ok?expf(v2-m):0.f);
    sEx += __shfl_xor(sEx,1,64);
    sEx += __shfl_xor(sEx,2,64);
    sEx += __shfl_xor(sEx,4,64);
    sEx += __shfl_xor(sEx,8,64);
    float lse = m + logf(sEx);
    if (rr < N){
      out[(size_t)rr*CC + c0]      = v0 - lse;
      out[(size_t)rr*CC + 16 + c0] = v1 - lse;
      if (v2ok) out[(size_t)rr*CC + 32 + c0] = v2 - lse;
    }
  }
}

extern "C" void kernel_launch(void* const* d_in, const int* in_sizes, int n_in,
                              void* d_out, int out_size, void* d_ws, size_t ws_size,
                              hipStream_t stream){
  const float* x = (const float*)d_in[0];
  const int* ei = (const int*)d_in[1];
  const float* Wl[LL]; const float* bl[LL];
  for (int i=0;i<LL;i++){ Wl[i]=(const float*)d_in[2+2*i]; bl[i]=(const float*)d_in[3+2*i]; }
  const float* Wlin = (const float*)d_in[2+2*LL];
  const float* blin = (const float*)d_in[3+2*LL];
  float* out = (float*)d_out;
  const int N = in_sizes[0]/FF;
  const int E = in_sizes[1]/2;
  const int NB = (N+CBSZ-1)/CBSZ;

  char* p = (char*)d_ws;
  auto alloc = [&](size_t bb)->char*{ char* r=p; p += (bb+255)&~(size_t)255; return r; };
  unsigned short* X   = (unsigned short*)alloc((size_t)N*XDIM*2);
  unsigned short* lin = (unsigned short*)alloc((size_t)(N+1)*64*2);  // +1 zero row
  unsigned* tmp = (unsigned*)lin;  // alias: tmp (8MB) dead before gbig writes lin
  unsigned short* WfBig  = (unsigned short*)alloc((size_t)16*28*512*2);  // 28-tile stride
  unsigned short* WfH[LL];   // index 1..5
  for (int i=1;i<LL;i++) WfH[i]=(unsigned short*)alloc((size_t)(2*i)*4*512*2);
  unsigned short* WfLinH = (unsigned short*)alloc((size_t)12*3*512*2);
  unsigned short* part[LL];  // index 1..5
  for (int i=1;i<LL;i++) part[i]=(unsigned short*)alloc((size_t)N*64*2);
  float* pF    = (float*)alloc((size_t)N*CC*4);
  float* dinv  = (float*)alloc((size_t)N*4);
  int* offsS   = (int*)alloc((size_t)N*4);
  int* offsE   = (int*)alloc((size_t)N*4);
  int* bcur    = (int*)alloc((size_t)NB*4);
  int* esrc    = (int*)alloc(((size_t)NB*SLACK+64)*4);

  PrepP P;
  P.x=x; P.ei=ei; P.X=X; P.lin=lin; P.bcur=bcur; P.tmp=tmp;
  int off=0, sg=0;
  for (int i=0;i<LL;i++){
    P.W[sg]=Wl[i]; P.dst[sg]=WfBig; P.nt[sg]=4; P.nc[sg]=HH;
    P.tst[sg]=28; P.tbs[sg]=4*i; P.kbase[sg]=0;
    P.off[sg]=off; off += 16*4*512; ++sg;
  }
  P.W[sg]=Wlin; P.dst[sg]=WfBig; P.nt[sg]=3; P.nc[sg]=CC;
  P.tst[sg]=28; P.tbs[sg]=24; P.kbase[sg]=0;
  P.off[sg]=off; off += 16*3*512; ++sg;
  for (int i=1;i<LL;i++){
    P.W[sg]=Wl[i]; P.dst[sg]=WfH[i]; P.nt[sg]=4; P.nc[sg]=HH;
    P.tst[sg]=4; P.tbs[sg]=0; P.kbase[sg]=FF;
    P.off[sg]=off; off += (2*i)*4*512; ++sg;
  }
  P.W[sg]=Wlin; P.dst[sg]=WfLinH; P.nt[sg]=3; P.nc[sg]=CC;
  P.tst[sg]=3; P.tbs[sg]=0; P.kbase[sg]=FF;
  P.off[sg]=off; off += 12*3*512; ++sg;
  P.off[sg]=off;
  P.N=N; P.E=E; P.CH=(E+255)/256; P.NB=NB; P.WB=(off+255)/256;
  int XB=(N*(FF/4)+255)/256;

  hipMemsetAsync(bcur, 0, (size_t)NB*4, stream);
  k_prep <<<256 + P.WB + XB, 256, 0, stream>>>(P);
  k_build<<<NB, 1024, 0, stream>>>(tmp, bcur, offsS, offsE, dinv, esrc, N);

  GBP G;
  G.X=X; G.WfBig=WfBig; G.dinv=dinv;
  G.pl[0]=lin;
  for (int i=1;i<LL;i++) G.pl[i]=part[i];
  G.pF=pF; G.N=N;
  k_gbig<<<(N+31)/32, 256, 0, stream>>>(G);

  int gb = (N+127)/128;
  int ab = (N+3)/4;
  for (int i=0;i<LL;i++){
    if (i>0) k_gemmH<<<gb,256,0,stream>>>(X, WfH[i], part[i], dinv, lin, N, 2*i);
    k_agg<<<ab,256,0,stream>>>(lin, offsS, offsE, esrc, dinv, bl[i], X, FF+HH*i, N);
  }
  k_final<<<(N+63)/64,256,0,stream>>>(X, WfLinH, pF, blin, out, N);
}